// Round 4
// baseline (397.558 us; speedup 1.0000x reference)
//
#include <hip/hip_runtime.h>

// EvidentialGNN: 2-layer GCN. evidence = softplus(gcn2(relu(gcn1(x)))).
// Outputs concatenated: (evidence[50000,64], h[50000,256]).
// R11 (= R10 with nt-store type fix): (a) GEMM A-convert via v_cvt_pk_bf16_f32
//      (1 instr / 2 elems, RNE) in the AF32 staging path; (b) GEMM1 tile
//      128x64 -> 1564 blocks (was 782, grid-starved); (c) nontemporal stores
//      (via ext_vector float4_t — HIP float4 rejected by the builtin) for pure
//      outputs (h fp32, evidence) so agg gather keeps L2; (d) self/bias loads
//      hoisted above edge loops; (e) both weight casts fused into one launch.

#define N_NODES 50000
#define IN_DIM 512
#define HID 256
#define NCLS 64

typedef unsigned short u16;
typedef unsigned int u32;
typedef __attribute__((ext_vector_type(8))) short short8;
typedef __attribute__((ext_vector_type(4))) float float4_t;

__device__ __forceinline__ float bf_lo(u32 v) {
    u32 u = v << 16; float f; __builtin_memcpy(&f, &u, 4); return f;
}
__device__ __forceinline__ float bf_hi(u32 v) {
    u32 u = v & 0xffff0000u; float f; __builtin_memcpy(&f, &u, 4); return f;
}
__device__ __forceinline__ u16 f2bf(float f) {   // RNE float->bf16
    u32 u; __builtin_memcpy(&u, &f, 4);
    return (u16)((u + 0x7fffu + ((u >> 16) & 1u)) >> 16);
}
__device__ __forceinline__ u32 pk_bf16(float lo, float hi) {  // HW RNE pack
    u32 r;
    asm("v_cvt_pk_bf16_f32 %0, %1, %2" : "=v"(r) : "v"(lo), "v"(hi));
    return r;
}
__device__ __forceinline__ void add8(float* acc, uint4 v) {
    acc[0] += bf_lo(v.x); acc[1] += bf_hi(v.x);
    acc[2] += bf_lo(v.y); acc[3] += bf_hi(v.y);
    acc[4] += bf_lo(v.z); acc[5] += bf_hi(v.z);
    acc[6] += bf_lo(v.w); acc[7] += bf_hi(v.w);
}
__device__ __forceinline__ void acc8(float* acc, uint4 v, float w) {
    acc[0] += w * bf_lo(v.x); acc[1] += w * bf_hi(v.x);
    acc[2] += w * bf_lo(v.y); acc[3] += w * bf_hi(v.y);
    acc[4] += w * bf_lo(v.z); acc[5] += w * bf_hi(v.z);
    acc[6] += w * bf_lo(v.w); acc[7] += w * bf_hi(v.w);
}
__device__ __forceinline__ void nt_store4(float* p, float a, float b, float c, float d) {
    float4_t v = {a, b, c, d};
    __builtin_nontemporal_store(v, (float4_t*)p);
}

// ---------------- graph prep ----------------
__global__ void init_kernel(int* __restrict__ cnt, int* __restrict__ cursor, int n) {
    int i = blockIdx.x * blockDim.x + threadIdx.x;
    if (i < n) { cnt[i] = 0; cursor[i] = 0; }
}

__global__ void count_kernel(const int* __restrict__ dst, int* __restrict__ cnt, int E) {
    int e = blockIdx.x * blockDim.x + threadIdx.x;
    if (e < E) atomicAdd(&cnt[dst[e]], 1);
}

// s1: per-block reduce of cnt -> blocksum; fused dinv = rsqrt(cnt+1).
__global__ __launch_bounds__(256) void s1_kernel(const int* __restrict__ cnt,
                                                 int* __restrict__ blocksum,
                                                 float* __restrict__ dinv, int n) {
    int tid = threadIdx.x;
    int i = blockIdx.x * 256 + tid;
    int c = (i < n) ? cnt[i] : 0;
    if (i < n) dinv[i] = rsqrtf((float)(c + 1));  // +1 self-loop
    __shared__ int s[256];
    s[tid] = c;
    __syncthreads();
    for (int off = 128; off > 0; off >>= 1) {
        if (tid < off) s[tid] += s[tid + off];
        __syncthreads();
    }
    if (tid == 0) blocksum[blockIdx.x] = s[0];
}

// s3 (fused s2): every block scans the <=256 block sums in LDS to get its own
// offset, then does the block-local exclusive scan -> row_ptr[0..n].
__global__ __launch_bounds__(256) void s3_kernel(const int* __restrict__ cnt,
                                                 const int* __restrict__ blocksum,
                                                 int* __restrict__ row_ptr, int n, int nb) {
    __shared__ int bs[256];
    __shared__ int s[256];
    int tid = threadIdx.x;
    int v = (tid < nb) ? blocksum[tid] : 0;
    bs[tid] = v;
    __syncthreads();
    for (int off = 1; off < 256; off <<= 1) {
        int a = (tid >= off) ? bs[tid - off] : 0;
        __syncthreads();
        bs[tid] += a;
        __syncthreads();
    }
    int boff = (blockIdx.x == 0) ? 0 : bs[blockIdx.x - 1];
    int i = blockIdx.x * 256 + tid;
    int c = (i < n) ? cnt[i] : 0;
    s[tid] = c;
    __syncthreads();
    for (int off = 1; off < 256; off <<= 1) {
        int a = (tid >= off) ? s[tid - off] : 0;
        __syncthreads();
        s[tid] += a;
        __syncthreads();
    }
    if (i <= n) row_ptr[i] = boff + s[tid] - c;
}

__global__ void fill_kernel(const int* __restrict__ src, const int* __restrict__ dst,
                            const int* __restrict__ row_ptr, int* __restrict__ cursor,
                            int* __restrict__ csr_src, int E) {
    int e = blockIdx.x * blockDim.x + threadIdx.x;
    if (e >= E) return;
    int d = dst[e];
    int pos = row_ptr[d] + atomicAdd(&cursor[d], 1);
    csr_src[pos] = src[e];
}

// ---------------- casts ----------------
// Both weight transposes in one launch.
// W1t[n][k] = bf16(W1[k][n]) for [512,256]; W2t[n][k] = bf16(W2[k][n]) [256,64].
__global__ __launch_bounds__(256) void tcast2_kernel(const float* __restrict__ W1,
                                                     u16* __restrict__ W1t,
                                                     const float* __restrict__ W2,
                                                     u16* __restrict__ W2t) {
    int idx = blockIdx.x * 256 + threadIdx.x;
    constexpr int N1 = IN_DIM * HID;
    if (idx < N1) {
        int n = idx / IN_DIM, k = idx - n * IN_DIM;
        W1t[idx] = f2bf(W1[k * HID + n]);
    } else {
        int j = idx - N1;
        if (j < HID * NCLS) {
            int n = j / HID, k = j - n * HID;
            W2t[j] = f2bf(W2[k * NCLS + n]);
        }
    }
}

// ---------------- bf16 MFMA GEMM (2-phase pipelined) ----------------
// C[M,N] = A[M,K] @ Bt[N,K]^T, fp32 accumulate, bf16 out.
// AF32: A is fp32, converted to bf16 in the A-staging (reg-stage + cvt_pk +
// ds_write). SCALE: epilogue multiplies each output row by rowscale[row].
// 256 threads = 2x2 waves; per-wave (BM/2)x(BN/2) via MRxNR 16x16x32 MFMA.
// BK=32, double-buffered LDS.
template <int BM, int BN, int K, int N, bool AF32, bool SCALE>
__global__ __launch_bounds__(256) void mfma_gemm_kernel(const void* __restrict__ Ain,
                                                        const u16* __restrict__ Bt,
                                                        u16* __restrict__ C, int M,
                                                        const float* __restrict__ rowscale) {
    constexpr int WROWS = 2, WCOLS = 2;
    constexpr int WMR = BM / WROWS;      // rows per wave
    constexpr int WNR = BN / WCOLS;      // cols per wave
    constexpr int MR = WMR / 16;         // A-frag repeat
    constexpr int NR = WNR / 16;         // B-frag repeat
    constexpr int AI = BM / 64;          // A staging iters
    constexpr int BI = BN / 64;          // B staging iters
    constexpr int LDSA = BM * 32;        // u16 per buffer
    constexpr int LDSB = BN * 32;
    constexpr int LDST = LDSA + LDSB;
    constexpr int NT = K / 32;
    static_assert(MR * 16 * WROWS == BM && NR * 16 * WCOLS == BN, "tiling");
    __shared__ u16 lds[2 * LDST];

    const int tid = threadIdx.x;
    const int wave = tid >> 6, lane = tid & 63;
    const int wm = wave / WCOLS, wn = wave % WCOLS;
    const int quad = lane >> 4, l15 = lane & 15;
    const int row0 = blockIdx.y * BM;
    const int col0 = blockIdx.x * BN;

    const float* Af = (const float*)Ain;
    const u16* Abf = (const u16*)Ain;

    // clamped global A rows for the staging lanes (computed once)
    int gra[AI];
#pragma unroll
    for (int i = 0; i < AI; i++) {
        int gr = row0 + ((tid + i * 256) >> 2);
        gra[i] = gr < M ? gr : M - 1;
    }

    float4 pa[AI][2];  // AF32: in-flight A fp32 for the next k-step

    auto loadA = [&](int k0) {  // AF32 only: issue global loads into pa
#pragma unroll
        for (int i = 0; i < AI; i++) {
            int c = tid + i * 256;
            const float* gp = Af + (long)gra[i] * K + k0 + (c & 3) * 8;
            pa[i][0] = ((const float4*)gp)[0];
            pa[i][1] = ((const float4*)gp)[1];
        }
    };
    auto writeA = [&](u16* buf) {  // AF32 only: cvt_pk + ds_write (waits pa)
#pragma unroll
        for (int i = 0; i < AI; i++) {
            int c = tid + i * 256;
            uint4 o;
            o.x = pk_bf16(pa[i][0].x, pa[i][0].y);
            o.y = pk_bf16(pa[i][0].z, pa[i][0].w);
            o.z = pk_bf16(pa[i][1].x, pa[i][1].y);
            o.w = pk_bf16(pa[i][1].z, pa[i][1].w);
            *(uint4*)(buf + c * 8) = o;
        }
    };
    auto stageA_lds = [&](int k0, u16* buf) {  // bf16 A via async global->LDS
#pragma unroll
        for (int i = 0; i < AI; i++) {
            int c = tid + i * 256;
            const u16* gp = Abf + (long)gra[i] * K + k0 + (c & 3) * 8;
            __builtin_amdgcn_global_load_lds((const __attribute__((address_space(1))) u32*)gp,
                                             (__attribute__((address_space(3))) u32*)(buf + c * 8),
                                             16, 0, 0);
        }
    };
    auto stageB = [&](int k0, u16* buf) {
#pragma unroll
        for (int i = 0; i < BI; i++) {
            int c = tid + i * 256;
            int r = c >> 2;
            const u16* gp = Bt + (long)(col0 + r) * K + k0 + (c & 3) * 8;
            __builtin_amdgcn_global_load_lds((const __attribute__((address_space(1))) u32*)gp,
                                             (__attribute__((address_space(3))) u32*)(buf + c * 8),
                                             16, 0, 0);
        }
    };

    float4_t acc[MR][NR];
#pragma unroll
    for (int mi = 0; mi < MR; mi++)
#pragma unroll
        for (int ni = 0; ni < NR; ni++) {
            float4_t z = {0.f, 0.f, 0.f, 0.f};
            acc[mi][ni] = z;
        }

    // prologue: stage t=0 into buffer 0
    if constexpr (AF32) {
        loadA(0);
        writeA(lds);
    } else {
        stageA_lds(0, lds);
    }
    stageB(0, lds + LDSA);
    __syncthreads();

    for (int t = 0; t < NT; t++) {
        u16* cur = lds + (t & 1) * LDST;
        u16* nxt = lds + ((t + 1) & 1) * LDST;
        const bool pre = (t + 1) < NT;
        if (pre) {  // issue next-tile loads first (latency hides under MFMA)
            if constexpr (AF32) loadA((t + 1) * 32);
            else stageA_lds((t + 1) * 32, nxt);
            stageB((t + 1) * 32, nxt + LDSA);
        }

        short8 af[MR], bfr[NR];
#pragma unroll
        for (int mi = 0; mi < MR; mi++)
            af[mi] = *(const short8*)(cur + (wm * WMR + mi * 16 + l15) * 32 + quad * 8);
#pragma unroll
        for (int ni = 0; ni < NR; ni++)
            bfr[ni] = *(const short8*)(cur + LDSA + (wn * WNR + ni * 16 + l15) * 32 + quad * 8);
#pragma unroll
        for (int mi = 0; mi < MR; mi++)
#pragma unroll
            for (int ni = 0; ni < NR; ni++)
                acc[mi][ni] = __builtin_amdgcn_mfma_f32_16x16x32_bf16(af[mi], bfr[ni],
                                                                      acc[mi][ni], 0, 0, 0);
        if (pre) {
            if constexpr (AF32) writeA(nxt);  // vmcnt wait lands after MFMA cluster
        }
        __syncthreads();
    }

#pragma unroll
    for (int mi = 0; mi < MR; mi++) {
#pragma unroll
        for (int r = 0; r < 4; r++) {
            int row = row0 + wm * WMR + mi * 16 + quad * 4 + r;
            if (row < M) {
                float sc = 1.f;
                if constexpr (SCALE) sc = rowscale[row];
#pragma unroll
                for (int ni = 0; ni < NR; ni++) {
                    int col = col0 + wn * WNR + ni * 16 + l15;
                    C[(long)row * N + col] = f2bf(acc[mi][ni][r] * sc);
                }
            }
        }
    }
}

// ---------------- agg1: wide rows (FEAT=256), one node per wave ----------------
// Rows in t are PRE-SCALED by dinv[src] (GEMM epilogue), so the inner loop is a
// pure row-sum: out = dinv[d]*(sum + self) + b.  32 lanes cover a 512B row with
// uint4; 2 edge groups; tiered unroll 16/8/2.  Self/bias hoisted; h fp32 via nt.
__global__ __launch_bounds__(256) void agg_wide_kernel(const u16* __restrict__ t,
                                                       const int* __restrict__ row_ptr,
                                                       const int* __restrict__ csr_src,
                                                       const float* __restrict__ dinv,
                                                       const float* __restrict__ bias,
                                                       float* __restrict__ out_f,
                                                       u16* __restrict__ out_bf, int n) {
    constexpr int FEAT = 256;
    int node = (blockIdx.x * blockDim.x + threadIdx.x) >> 6;
    int lane = threadIdx.x & 63;
    if (node >= n) return;
    const int g = lane >> 5;       // edge group 0..1
    const int r = lane & 31;       // lane within row

    // hoisted: self row, bias, dinv (latency hidden under the edge loop)
    const float di = dinv[node];
    uint4 sv = *(const uint4*)(t + (long)node * FEAT + r * 8);
    float4 b0 = *(const float4*)(bias + r * 8);
    float4 b1 = *(const float4*)(bias + r * 8 + 4);

    float acc[8] = {};
    const int beg = row_ptr[node], end = row_ptr[node + 1];
    int e = beg;
    for (; e + 16 <= end; e += 16) {   // 8 edges per group, 16 chains in flight
        int s[8]; uint4 v[8];
#pragma unroll
        for (int u = 0; u < 8; u++) s[u] = csr_src[e + u * 2 + g];
#pragma unroll
        for (int u = 0; u < 8; u++) v[u] = *(const uint4*)(t + (long)s[u] * FEAT + r * 8);
#pragma unroll
        for (int u = 0; u < 8; u++) add8(acc, v[u]);
    }
    for (; e + 8 <= end; e += 8) {
        int s[4]; uint4 v[4];
#pragma unroll
        for (int u = 0; u < 4; u++) s[u] = csr_src[e + u * 2 + g];
#pragma unroll
        for (int u = 0; u < 4; u++) v[u] = *(const uint4*)(t + (long)s[u] * FEAT + r * 8);
#pragma unroll
        for (int u = 0; u < 4; u++) add8(acc, v[u]);
    }
    for (; e < end; e += 2) {
        int ee = e + g;
        if (ee < end) {
            int s = csr_src[ee];
            uint4 v = *(const uint4*)(t + (long)s * FEAT + r * 8);
            add8(acc, v);
        }
    }
#pragma unroll
    for (int j = 0; j < 8; j++) acc[j] += __shfl_xor(acc[j], 32, 64);

    if (lane < 32) {
        float self[8] = {bf_lo(sv.x), bf_hi(sv.x), bf_lo(sv.y), bf_hi(sv.y),
                         bf_lo(sv.z), bf_hi(sv.z), bf_lo(sv.w), bf_hi(sv.w)};
        float bb[8] = {b0.x, b0.y, b0.z, b0.w, b1.x, b1.y, b1.z, b1.w};
        float rv[8];
#pragma unroll
        for (int j = 0; j < 8; j++)
            rv[j] = fmaxf(di * (acc[j] + self[j]) + bb[j], 0.f);  // relu
        long base = (long)node * FEAT + lane * 8;
        nt_store4(out_f + base, rv[0], rv[1], rv[2], rv[3]);
        nt_store4(out_f + base + 4, rv[4], rv[5], rv[6], rv[7]);
        uint4 o;
        o.x = pk_bf16(rv[0], rv[1]);
        o.y = pk_bf16(rv[2], rv[3]);
        o.z = pk_bf16(rv[4], rv[5]);
        o.w = pk_bf16(rv[6], rv[7]);
        *(uint4*)(out_bf + base) = o;   // re-read by GEMM2: keep cached
    }
}

// ---------------- agg2: narrow rows (FEAT=64), 8 nodes per wave ----------------
// Rows in t are PRE-SCALED by dinv[src].  8 lanes x 16B cover a 128B row; each
// 8-lane group owns one node; 4 edges in flight per group (w=1/0 masks tails).
__global__ __launch_bounds__(256) void agg_n8_kernel(const u16* __restrict__ t,
                                                     const int* __restrict__ row_ptr,
                                                     const int* __restrict__ csr_src,
                                                     const float* __restrict__ dinv,
                                                     const float* __restrict__ bias,
                                                     float* __restrict__ out_f, int n) {
    constexpr int FEAT = 64;
    const int wid = (blockIdx.x * blockDim.x + threadIdx.x) >> 6;
    const int lane = threadIdx.x & 63;
    const int g = lane >> 3;   // node group 0..7
    const int r = lane & 7;    // lane within row
    const int node = wid * 8 + g;
    const bool valid = node < n;
    const int nd = valid ? node : (n - 1);
    const int beg = row_ptr[nd];
    const int deg = valid ? (row_ptr[nd + 1] - beg) : 0;

    // hoisted: self row, bias, dinv
    const float di = dinv[nd];
    uint4 sv = *(const uint4*)(t + (long)nd * FEAT + r * 8);
    float4 b0 = *(const float4*)(bias + r * 8);
    float4 b1 = *(const float4*)(bias + r * 8 + 4);

    float acc[8] = {};
    for (int e = 0;; e += 4) {
        if (!__any(e < deg)) break;
        int s[4]; float w[4]; uint4 v[4];
#pragma unroll
        for (int u = 0; u < 4; u++) {
            bool a = (e + u) < deg;
            s[u] = a ? csr_src[beg + e + u] : 0;
            w[u] = a ? 1.f : 0.f;
        }
#pragma unroll
        for (int u = 0; u < 4; u++) v[u] = *(const uint4*)(t + (long)s[u] * FEAT + r * 8);
#pragma unroll
        for (int u = 0; u < 4; u++) acc8(acc, v[u], w[u]);  // w=0 kills garbage rows
    }
    float self[8] = {bf_lo(sv.x), bf_hi(sv.x), bf_lo(sv.y), bf_hi(sv.y),
                     bf_lo(sv.z), bf_hi(sv.z), bf_lo(sv.w), bf_hi(sv.w)};
    float bb[8] = {b0.x, b0.y, b0.z, b0.w, b1.x, b1.y, b1.z, b1.w};
    float rv[8];
#pragma unroll
    for (int j = 0; j < 8; j++) {
        float v = di * (acc[j] + self[j]) + bb[j];
        // fast softplus: max(v,0) + ln(1+exp(-|v|)) via v_exp/v_log
        rv[j] = fmaxf(v, 0.f) + __logf(1.f + __expf(-fabsf(v)));
    }
    if (valid) {
        long base = (long)nd * FEAT + r * 8;
        nt_store4(out_f + base, rv[0], rv[1], rv[2], rv[3]);
        nt_store4(out_f + base + 4, rv[4], rv[5], rv[6], rv[7]);
    }
}

extern "C" void kernel_launch(void* const* d_in, const int* in_sizes, int n_in,
                              void* d_out, int out_size, void* d_ws, size_t ws_size,
                              hipStream_t stream) {
    const float* x  = (const float*)d_in[0];
    const int*   ei = (const int*)d_in[1];
    const float* W1 = (const float*)d_in[2];
    const float* b1 = (const float*)d_in[3];
    const float* W2 = (const float*)d_in[4];
    const float* b2 = (const float*)d_in[5];

    float* evidence = (float*)d_out;                        // [50000, 64]
    float* h        = (float*)d_out + (long)N_NODES * NCLS; // [50000, 256]

    const int E = in_sizes[1] / 2;
    const int* src = ei;
    const int* dst = ei + E;

    const int NB = (N_NODES + 255) / 256;  // 196 scan blocks

    // workspace carve-up (16B-aligned regions)
    char* w = (char*)d_ws;
    int*   cnt      = (int*)w;  w += 50048 * 4;
    int*   cursor   = (int*)w;  w += 50048 * 4;
    int*   row_ptr  = (int*)w;  w += 50064 * 4;
    float* dinv     = (float*)w; w += 50048 * 4;
    int*   blocksum = (int*)w;  w += 256 * 4;
    int*   csr_src  = (int*)w;  w += 800000 * 4;
    u16*   hbf      = (u16*)w;  w += (long)N_NODES * IN_DIM * 2;  // h bf16 (only HID used)
    u16*   w1t      = (u16*)w;  w += IN_DIM * HID * 2;
    u16*   w2t      = (u16*)w;  w += HID * NCLS * 2;
    u16*   t1bf     = (u16*)w;  w += (long)N_NODES * HID * 2;     // reused as t2_bf
    u16*   t2bf     = t1bf;

    // graph prep
    init_kernel<<<NB, 256, 0, stream>>>(cnt, cursor, N_NODES);
    count_kernel<<<(E + 255) / 256, 256, 0, stream>>>(dst, cnt, E);
    s1_kernel<<<NB, 256, 0, stream>>>(cnt, blocksum, dinv, N_NODES);
    s3_kernel<<<NB, 256, 0, stream>>>(cnt, blocksum, row_ptr, N_NODES, NB);
    fill_kernel<<<(E + 255) / 256, 256, 0, stream>>>(src, dst, row_ptr, cursor, csr_src, E);

    // weight casts (fused)
    {
        int tot = IN_DIM * HID + HID * NCLS;
        tcast2_kernel<<<(tot + 255) / 256, 256, 0, stream>>>(W1, w1t, W2, w2t);
    }

    // layer 1: t1 = dinv .* (x @ W1)  (fp32 A fused-cast, scaled epilogue);
    //          h = relu(dinv[d]*(sum t1[s] + t1[d]) + b1), also h_bf
    {
        dim3 grid(HID / 64, (N_NODES + 127) / 128);   // 4 x 391 = 1564 blocks
        mfma_gemm_kernel<128, 64, IN_DIM, HID, true, true>
            <<<grid, 256, 0, stream>>>(x, w1t, t1bf, N_NODES, dinv);
    }
    agg_wide_kernel<<<(N_NODES * 64 + 255) / 256, 256, 0, stream>>>(
        t1bf, row_ptr, csr_src, dinv, b1, h, hbf, N_NODES);

    // layer 2: t2 = dinv .* (h @ W2); evidence = softplus(dinv[d]*(sum+self) + b2)
    {
        dim3 grid(NCLS / 64, (N_NODES + 63) / 64);    // 1 x 782
        mfma_gemm_kernel<64, 64, HID, NCLS, false, true>
            <<<grid, 256, 0, stream>>>(hbf, w2t, t2bf, N_NODES, dinv);
    }
    {
        int waves = (N_NODES + 7) / 8;                 // 6250 waves
        int blocks = (waves + 3) / 4;                  // 4 waves per block
        agg_n8_kernel<<<blocks, 256, 0, stream>>>(
            t2bf, row_ptr, csr_src, dinv, b2, evidence, N_NODES);
    }
}